// Round 10
// baseline (1338.533 us; speedup 1.0000x reference)
//
#include <hip/hip_runtime.h>
#include <hip/hip_bf16.h>
#include <hip/hip_cooperative_groups.h>

namespace cg = cooperative_groups;

// 2-layer GCN encoder: (GCNConv -> BatchNorm1d(train) -> PReLU) x 2
// N=50000, E=800000, D=128. Inputs f32 (probed), edge_index int64 (probed),
// output f32. Internal: GEMM/agg buffers bf16, math f32.
//
// R10: dispatch-count attack (17 -> 5, ~10us/dispatch overhead measured by
// ledger gap). (1) whole CSR build = ONE cooperative kernel; rowptr now comes
// from bucket-base + intra-bucket LDS prefix scan (global scans + deg[] die).
// (2) agg+stats (+apply) fused into cooperative k_post1/k_post2 (1024 blocks,
// grid-stride; VGPR<=64 so 4 blocks/CU co-residency is safe).
// (3) GEMMs standalone (128 VGPR must not cap agg occupancy); W staged+swizzled
// in-kernel again (k_prep dies).
//
// ws layout (bytes):
//   [0       .. +200000)   dinv f32[NN]
//   [200704  .. +8)        flags: [0]=int64?, [1]=bf16-floats?
//   [201728  .. +1024)     stats1 (sum[128], sumsq[128])
//   [202752  .. +1024)     stats2
//   [404800  .. +200004)   rowptr int[NN+1]
//   [604816  .. +200000)   fill  int[NN]
//   [805632  .. +256)      tail int[64]
//   [805888  .. +256)      bcnt int[64]
//   [806144  .. +260)      bbase int[65]
//   [1048576 .. +3.2MB)    csr_src int[NE]
//   [4456448 .. +12.8MB)   hbuf  bf16[NN*DD] packed-slot layout (dinv-scaled)
//   [30056448.. +12.8MB)   aggbuf bf16[NN*DD] row-major
//   [42856448.. +6.4MB)    binned uint2[NE]

typedef __hip_bfloat16 bf16;
typedef __attribute__((ext_vector_type(8))) short short8;   // 8 bf16 = 4 VGPR
typedef __attribute__((ext_vector_type(4))) float f32x4;    // MFMA accumulator

#define NN 50000
#define NE 800000
#define DD 128
#define BN_EPS 1e-5f
#define BIN_CHUNK 3125   // NE / 256 exactly

__device__ __forceinline__ float b2f(bf16 v) { return __bfloat162float(v); }
__device__ __forceinline__ float ldf(const void* p, size_t idx, int isbf) {
  return isbf ? b2f(((const bf16*)p)[idx]) : ((const float*)p)[idx];
}
__device__ __forceinline__ int lde(const void* ei, size_t idx, int is64) {
  return is64 ? (int)((const long long*)ei)[idx] : ((const int*)ei)[idx];
}
__device__ __forceinline__ unsigned int f2bs(float v) {
  bf16 b = __float2bfloat16(v);
  return (unsigned int)*reinterpret_cast<unsigned short*>(&b);
}
__device__ __forceinline__ float bslo(unsigned int u) { return __uint_as_float(u << 16); }
__device__ __forceinline__ float bshi(unsigned int u) { return __uint_as_float(u & 0xFFFF0000u); }
__device__ __forceinline__ float s2f(short v) {
  return __uint_as_float(((unsigned int)(unsigned short)v) << 16);
}

// ---------------- cooperative CSR build: 256 blocks x 256 thr ----------------
// P0 detect+zeros | P1 bcount | P2 bscan | P3 bin | P4 bucket hist -> dinv/
// rowptr/fill (intra-bucket scan; bucket base == edge base) | P5 fill2
__global__ __launch_bounds__(256) void k_build(const int* ei_i, const unsigned short* x16,
                                               int* flags, int* bcnt, int* bbase, int* tail,
                                               uint2* binned, float* dinv, int* rowptr,
                                               int* fill, int* csr_src,
                                               float* stats1, float* stats2) {
  cg::grid_group grid = cg::this_grid();
  __shared__ int sm[1280];
  const int tid = threadIdx.x;
  const int bid = blockIdx.x;
  const void* ei = (const void*)ei_i;

  // P0: dtype probes + zero stats/bcnt
  if (bid == 0 && tid < 64) {
    unsigned long long m1 = __ballot(ei_i[2 * tid + 1] != 0);
    int ex = (x16[2 * tid] >> 7) & 0xFF;
    unsigned long long m2 = __ballot(ex >= 90 && ex <= 140);
    if (tid == 0) {
      flags[0] = (m1 == 0ull) ? 1 : 0;
      flags[1] = (__popcll(m2) >= 48) ? 1 : 0;
    }
  }
  if (bid == 1) stats1[tid] = 0.f;
  if (bid == 2) stats2[tid] = 0.f;
  if (bid == 3 && tid < 64) bcnt[tid] = 0;
  __threadfence();
  grid.sync();

  const int is64 = flags[0];

  // P1: bucket-level histogram of dst>>10
  {
    int* cnt = sm;
    if (tid < 64) cnt[tid] = 0;
    __syncthreads();
    const int e0 = bid * BIN_CHUNK;
    for (int t = tid; t < BIN_CHUNK; t += 256) {
      int d = lde(ei, (size_t)NE + e0 + t, is64);
      atomicAdd(&cnt[d >> 10], 1);
    }
    __syncthreads();
    if (tid < 64 && cnt[tid]) atomicAdd(&bcnt[tid], cnt[tid]);
  }
  __threadfence();
  grid.sync();

  // P2: exclusive scan of bcnt[64] -> bbase, seed tail (block 0)
  if (bid == 0) {
    int v = (tid < 64) ? bcnt[tid] : 0;
    sm[tid] = v;
    __syncthreads();
    for (int off = 1; off < 64; off <<= 1) {
      int u = (tid >= off && tid < 64) ? sm[tid - off] : 0;
      __syncthreads();
      if (tid < 64) sm[tid] += u;
      __syncthreads();
    }
    if (tid < 64) {
      int ex = sm[tid] - v;
      bbase[tid] = ex;
      tail[tid] = ex;
    }
    if (tid == 63) bbase[64] = sm[63];  // == NE
  }
  __threadfence();
  grid.sync();

  // P3: bin edges by dst-bucket into binned[] (per-block reserved segments)
  {
    int* cnt = sm;
    int* cur = sm + 64;
    int* gb = sm + 128;
    if (tid < 64) { cnt[tid] = 0; cur[tid] = 0; }
    __syncthreads();
    const int e0 = bid * BIN_CHUNK;
    for (int t = tid; t < BIN_CHUNK; t += 256) {
      int d = lde(ei, (size_t)NE + e0 + t, is64);
      atomicAdd(&cnt[d >> 10], 1);
    }
    __syncthreads();
    if (tid < 64 && cnt[tid] > 0) gb[tid] = atomicAdd(&tail[tid], cnt[tid]);
    __syncthreads();
    for (int t = tid; t < BIN_CHUNK; t += 256) {
      int s = lde(ei, (size_t)(e0 + t), is64);
      int d = lde(ei, (size_t)NE + e0 + t, is64);
      int b = d >> 10;
      int r = atomicAdd(&cur[b], 1);
      binned[gb[b] + r] = make_uint2((unsigned)s, (unsigned)d);
    }
  }
  __threadfence();
  grid.sync();

  // P4: per-bucket degree hist (LDS) -> dinv; rowptr/fill = bucket edge base
  // + intra-bucket exclusive prefix (valid because binned is bucket-major).
  for (int b = bid; b < 49; b += gridDim.x) {
    int* hist = sm;        // 1024
    int* ss = sm + 1024;   // 256
    for (int i = tid; i < 1024; i += 256) hist[i] = 0;
    __syncthreads();
    const int eb = bbase[b], ee = bbase[b + 1];
    for (int e = eb + tid; e < ee; e += 256) atomicAdd(&hist[binned[e].y & 1023], 1);
    __syncthreads();
    int h0 = hist[tid * 4], h1 = hist[tid * 4 + 1], h2 = hist[tid * 4 + 2], h3 = hist[tid * 4 + 3];
    int local = h0 + h1 + h2 + h3;
    ss[tid] = local;
    __syncthreads();
    for (int off = 1; off < 256; off <<= 1) {
      int u = (tid >= off) ? ss[tid - off] : 0;
      __syncthreads();
      ss[tid] += u;
      __syncthreads();
    }
    int p = eb + ss[tid] - local;  // exclusive
    int node = b * 1024 + tid * 4;
    int hh[4] = {h0, h1, h2, h3};
#pragma unroll
    for (int j = 0; j < 4; j++) {
      if (node + j < NN) {
        rowptr[node + j] = p;
        fill[node + j] = p;
        dinv[node + j] = rsqrtf((float)(hh[j] + 1));  // +1 self-loop
      }
      p += hh[j];
    }
  }
  if (bid == 0 && tid == 0) rowptr[NN] = NE;
  __threadfence();
  grid.sync();

  // P5: exact CSR fill (writes confined to ~65KB L2-resident dst windows)
  for (int e = bid * 256 + tid; e < NE; e += gridDim.x * 256) {
    uint2 u = binned[e];
    int pos = atomicAdd(&fill[u.y], 1);
    csr_src[pos] = (int)u.x;
  }
}

// ---------------- MFMA GEMM (standalone; 391 blocks x 256) ----------------
// out = dinv-prescaled bf16 in packed-slot layout: row r, u32 slot s holds
// bf16 pair (col s, col s+64). W staged+swizzled to LDS in-kernel.
// XMODE 0: layer-1 input (probe f32/bf16). XMODE 2: aggbuf bf16 + fused BN1.
template <int XMODE>
__global__ __launch_bounds__(256) void k_gemm(const void* in_, const void* W,
                                              const int* flags, const float* dinv,
                                              const float* stats, const void* g,
                                              const void* be, const void* al,
                                              unsigned int* out) {
  __shared__ alignas(16) short sW[16 * 128 * 8];  // 32 KB
  __shared__ float sSc[DD], sSh[DD], sAl;
  const int isbf = flags[1];
  const int tid = threadIdx.x;

  for (int idx = tid; idx < DD * DD; idx += 256) {
    int k = idx >> 7, n = idx & 127;
    sW[(k >> 3) * 1024 + n * 8 + (k & 7)] = (short)f2bs(ldf(W, idx, isbf));
  }
  if (XMODE == 2) {
    if (tid < DD) {
      const float inv_n = 1.0f / NN;
      float mu = stats[tid] * inv_n;
      float var = stats[DD + tid] * inv_n - mu * mu;
      float sc = rsqrtf(var + BN_EPS) * ldf(g, tid, isbf);
      sSc[tid] = sc;
      sSh[tid] = ldf(be, tid, isbf) - mu * sc;
    }
    if (tid == 0) sAl = ldf(al, 0, isbf);
  }
  __syncthreads();

  const int wave = tid >> 6;
  const int lane = tid & 63;
  const int quad = lane >> 4;
  const int m16 = lane & 15;
  const int r0 = blockIdx.x * 128 + wave * 32;

  f32x4 acc[2][8];
#pragma unroll
  for (int t = 0; t < 2; t++)
#pragma unroll
    for (int n = 0; n < 8; n++) acc[t][n] = (f32x4){0.f, 0.f, 0.f, 0.f};

#pragma unroll
  for (int q = 0; q < 4; q++) {
    const int kq = q * 32 + quad * 8;
    short8 af[2];
#pragma unroll
    for (int t = 0; t < 2; t++) {
      int row = r0 + t * 16 + m16;
      row = row < NN ? row : NN - 1;  // clamp; garbage rows never stored
      if (XMODE == 2) {
        short8 raw = *(const short8*)((const short*)in_ + (size_t)row * DD + kq);
        short8 f;
#pragma unroll
        for (int jj = 0; jj < 8; jj++) {
          float y = s2f(raw[jj]);
          y = y * sSc[kq + jj] + sSh[kq + jj];
          y = y > 0.f ? y : sAl * y;
          f[jj] = (short)f2bs(y);
        }
        af[t] = f;
      } else if (isbf) {
        af[t] = *(const short8*)((const short*)in_ + (size_t)row * DD + kq);
      } else {
        const float* ap = (const float*)in_ + (size_t)row * DD + kq;
        const float4 u0 = *(const float4*)ap;
        const float4 u1 = *(const float4*)(ap + 4);
        float v[8] = {u0.x, u0.y, u0.z, u0.w, u1.x, u1.y, u1.z, u1.w};
        short8 f;
#pragma unroll
        for (int jj = 0; jj < 8; jj++) f[jj] = (short)f2bs(v[jj]);
        af[t] = f;
      }
    }
    const int c = q * 4 + quad;
    const short* bp = sW + c * 1024 + m16 * 8;
#pragma unroll
    for (int n = 0; n < 8; n++) {
      const short8 bfrag = *(const short8*)(bp + n * 128);
      acc[0][n] = __builtin_amdgcn_mfma_f32_16x16x32_bf16(af[0], bfrag, acc[0][n], 0, 0, 0);
      acc[1][n] = __builtin_amdgcn_mfma_f32_16x16x32_bf16(af[1], bfrag, acc[1][n], 0, 0, 0);
    }
  }

#pragma unroll
  for (int t = 0; t < 2; t++)
#pragma unroll
    for (int r = 0; r < 4; r++) {
      int row = r0 + t * 16 + quad * 4 + r;
      if (row < NN) {
        float di = dinv[row];
        unsigned int* orow = out + (size_t)row * 64;
#pragma unroll
        for (int n = 0; n < 4; n++) {
          unsigned int p = (f2bs(di * acc[t][n + 4][r]) << 16) | f2bs(di * acc[t][n][r]);
          orow[n * 16 + m16] = p;
        }
      }
    }
}

// ------------- cooperative post: agg -> stats [-> apply] (1024 x 256) -------------
template <bool FINAL>
__device__ __forceinline__ void post_body(const unsigned int* hs, const float* dinv,
                                          const int* rowptr, const int* csr_src,
                                          const void* bias, const int* flags,
                                          unsigned short* aggbuf, float* stats,
                                          const void* g, const void* be, const void* al,
                                          void* dout) {
  cg::grid_group grid = cg::this_grid();
  const int tid = threadIdx.x;
  const int lane = tid & 63;
  const int isbf = flags[1];

  // Phase A: agg, grid-stride by wave (one wave per node)
  const int gw = (blockIdx.x * 256 + tid) >> 6;
  const int nw = gridDim.x * 4;
  for (int w = gw; w < NN; w += nw) {
    float dd_ = dinv[w];
    unsigned int hv = hs[(size_t)w * 64 + lane];
    float ax = bslo(hv), ay = bshi(hv);
    int e = rowptr[w], e1 = rowptr[w + 1];
    for (; e + 7 < e1; e += 8) {
      int s0 = csr_src[e], s1 = csr_src[e + 1], s2 = csr_src[e + 2], s3 = csr_src[e + 3];
      int s4 = csr_src[e + 4], s5 = csr_src[e + 5], s6 = csr_src[e + 6], s7 = csr_src[e + 7];
      unsigned int v0 = hs[(size_t)s0 * 64 + lane];
      unsigned int v1 = hs[(size_t)s1 * 64 + lane];
      unsigned int v2 = hs[(size_t)s2 * 64 + lane];
      unsigned int v3 = hs[(size_t)s3 * 64 + lane];
      unsigned int v4 = hs[(size_t)s4 * 64 + lane];
      unsigned int v5 = hs[(size_t)s5 * 64 + lane];
      unsigned int v6 = hs[(size_t)s6 * 64 + lane];
      unsigned int v7 = hs[(size_t)s7 * 64 + lane];
      ax += bslo(v0) + bslo(v1) + bslo(v2) + bslo(v3) + bslo(v4) + bslo(v5) + bslo(v6) + bslo(v7);
      ay += bshi(v0) + bshi(v1) + bshi(v2) + bshi(v3) + bshi(v4) + bshi(v5) + bshi(v6) + bshi(v7);
    }
    for (; e + 3 < e1; e += 4) {
      int s0 = csr_src[e], s1 = csr_src[e + 1], s2 = csr_src[e + 2], s3 = csr_src[e + 3];
      unsigned int v0 = hs[(size_t)s0 * 64 + lane];
      unsigned int v1 = hs[(size_t)s1 * 64 + lane];
      unsigned int v2 = hs[(size_t)s2 * 64 + lane];
      unsigned int v3 = hs[(size_t)s3 * 64 + lane];
      ax += bslo(v0) + bslo(v1) + bslo(v2) + bslo(v3);
      ay += bshi(v0) + bshi(v1) + bshi(v2) + bshi(v3);
    }
    for (; e < e1; e++) {
      unsigned int v0 = hs[(size_t)csr_src[e] * 64 + lane];
      ax += bslo(v0);
      ay += bshi(v0);
    }
    unsigned short* orow = aggbuf + (size_t)w * DD;
    orow[lane] = (unsigned short)f2bs(dd_ * ax + ldf(bias, lane, isbf));
    orow[lane + 64] = (unsigned short)f2bs(dd_ * ay + ldf(bias, lane + 64, isbf));
  }
  __threadfence();
  grid.sync();

  // Phase B: BN stats (col pair per thread, LDS reduce, 4 atomics/col-pair)
  {
    __shared__ float rsx[256], rsy[256], rqx[256], rqy[256];
    const unsigned int* x32 = (const unsigned int*)aggbuf;
    int c = tid & 63;
    float sx = 0.f, sy = 0.f, qx = 0.f, qy = 0.f;
    for (int r = blockIdx.x * 4 + (tid >> 6); r < NN; r += gridDim.x * 4) {
      unsigned int u = x32[(size_t)r * 64 + c];
      float a = bslo(u), b = bshi(u);
      sx += a; qx += a * a;
      sy += b; qy += b * b;
    }
    rsx[tid] = sx; rsy[tid] = sy; rqx[tid] = qx; rqy[tid] = qy;
    __syncthreads();
    if (tid < 64) {
      sx = rsx[tid] + rsx[tid + 64] + rsx[tid + 128] + rsx[tid + 192];
      sy = rsy[tid] + rsy[tid + 64] + rsy[tid + 128] + rsy[tid + 192];
      qx = rqx[tid] + rqx[tid + 64] + rqx[tid + 128] + rqx[tid + 192];
      qy = rqy[tid] + rqy[tid + 64] + rqy[tid + 128] + rqy[tid + 192];
      atomicAdd(&stats[2 * tid], sx);
      atomicAdd(&stats[2 * tid + 1], sy);
      atomicAdd(&stats[DD + 2 * tid], qx);
      atomicAdd(&stats[DD + 2 * tid + 1], qy);
    }
  }

  if (FINAL) {
    __threadfence();
    grid.sync();
    // Phase C: BN+PReLU -> d_out (f32 unless inputs were bf16)
    const float inv_n = 1.0f / NN;
    float alpha = ldf(al, 0, isbf);
    const uint2* x2 = (const uint2*)aggbuf;
    for (int i4 = blockIdx.x * 256 + tid; i4 < NN * 32; i4 += gridDim.x * 256) {
      int jq = (i4 & 31) * 4;
      const uint2 xv = x2[i4];
      float xa[4] = {bslo(xv.x), bshi(xv.x), bslo(xv.y), bshi(xv.y)};
      float y[4];
#pragma unroll
      for (int u = 0; u < 4; u++) {
        int j = jq + u;
        float mu = stats[j] * inv_n;
        float var = stats[DD + j] * inv_n - mu * mu;
        float sc = rsqrtf(var + BN_EPS) * ldf(g, j, isbf);
        float v = (xa[u] - mu) * sc + ldf(be, j, isbf);
        y[u] = v > 0.f ? v : alpha * v;
      }
      if (isbf) {
        uint2 o;
        o.x = (f2bs(y[1]) << 16) | f2bs(y[0]);
        o.y = (f2bs(y[3]) << 16) | f2bs(y[2]);
        ((uint2*)dout)[i4] = o;
      } else {
        float4 o = {y[0], y[1], y[2], y[3]};
        ((float4*)dout)[i4] = o;
      }
    }
  }
}

__global__ __launch_bounds__(256) void k_post1(const unsigned int* hs, const float* dinv,
                                               const int* rowptr, const int* csr_src,
                                               const void* bias, const int* flags,
                                               unsigned short* aggbuf, float* stats,
                                               const void* g, const void* be, const void* al,
                                               void* dout) {
  post_body<false>(hs, dinv, rowptr, csr_src, bias, flags, aggbuf, stats, g, be, al, dout);
}

__global__ __launch_bounds__(256) void k_post2(const unsigned int* hs, const float* dinv,
                                               const int* rowptr, const int* csr_src,
                                               const void* bias, const int* flags,
                                               unsigned short* aggbuf, float* stats,
                                               const void* g, const void* be, const void* al,
                                               void* dout) {
  post_body<true>(hs, dinv, rowptr, csr_src, bias, flags, aggbuf, stats, g, be, al, dout);
}

extern "C" void kernel_launch(void* const* d_in, const int* in_sizes, int n_in,
                              void* d_out, int out_size, void* d_ws, size_t ws_size,
                              hipStream_t stream) {
  const void* x = d_in[0];
  const int* ei = (const int*)d_in[1];
  const void* W1 = d_in[2];
  const void* b1 = d_in[3];
  const void* g1 = d_in[4];
  const void* be1 = d_in[5];
  const void* a1 = d_in[6];
  const void* W2 = d_in[7];
  const void* b2 = d_in[8];
  const void* g2 = d_in[9];
  const void* be2 = d_in[10];
  const void* a2 = d_in[11];

  char* w = (char*)d_ws;
  float* dinv = (float*)w;                              // 200000
  int* flags = (int*)(w + 200704);                      // 8
  float* stats1 = (float*)(w + 201728);                 // 1024
  float* stats2 = (float*)(w + 202752);                 // 1024
  int* rowptr = (int*)(w + 404800);                     // 200004
  int* fill = (int*)(w + 604816);                       // 200000
  int* tail = (int*)(w + 805632);                       // 256
  int* bcnt = (int*)(w + 805888);                       // 256
  int* bbase = (int*)(w + 806144);                      // 260
  int* csr_src = (int*)(w + 1048576);                   // 3200000
  unsigned int* hbuf = (unsigned int*)(w + 4456448);    // 12800000 (packed slots)
  unsigned short* aggbuf = (unsigned short*)(w + 30056448);  // 12800000 bf16 row-major
  uint2* binned = (uint2*)(w + 42856448);               // 6400000

  const int NB_G = (NN + 127) / 128;   // 391

  const unsigned short* x16 = (const unsigned short*)x;
  void* argsB[] = {(void*)&ei, (void*)&x16, (void*)&flags, (void*)&bcnt, (void*)&bbase,
                   (void*)&tail, (void*)&binned, (void*)&dinv, (void*)&rowptr, (void*)&fill,
                   (void*)&csr_src, (void*)&stats1, (void*)&stats2};
  hipLaunchCooperativeKernel((void*)k_build, dim3(256), dim3(256), argsB, 0, stream);

  // ---- layer 1 ----
  k_gemm<0><<<dim3(NB_G), dim3(256), 0, stream>>>(x, W1, flags, dinv,
                                                  nullptr, nullptr, nullptr, nullptr, hbuf);
  {
    const unsigned int* hs = hbuf;
    void* args1[] = {(void*)&hs, (void*)&dinv, (void*)&rowptr, (void*)&csr_src, (void*)&b1,
                     (void*)&flags, (void*)&aggbuf, (void*)&stats1, (void*)&g1, (void*)&be1,
                     (void*)&a1, (void*)&d_out};
    hipLaunchCooperativeKernel((void*)k_post1, dim3(1024), dim3(256), args1, 0, stream);
  }

  // ---- layer 2 (BN1+PReLU fused into GEMM A-path via stats1) ----
  k_gemm<2><<<dim3(NB_G), dim3(256), 0, stream>>>(aggbuf, W2, flags, dinv,
                                                  stats1, g1, be1, a1, hbuf);
  {
    const unsigned int* hs = hbuf;
    void* args2[] = {(void*)&hs, (void*)&dinv, (void*)&rowptr, (void*)&csr_src, (void*)&b2,
                     (void*)&flags, (void*)&aggbuf, (void*)&stats2, (void*)&g2, (void*)&be2,
                     (void*)&a2, (void*)&d_out};
    hipLaunchCooperativeKernel((void*)k_post2, dim3(1024), dim3(256), args2, 0, stream);
  }
}

// Round 11
// 315.065 us; speedup vs baseline: 4.2484x; 4.2484x over previous
//
#include <hip/hip_runtime.h>
#include <hip/hip_bf16.h>

// 2-layer GCN encoder: (GCNConv -> BatchNorm1d(train) -> PReLU) x 2
// N=50000, E=800000, D=128. Inputs f32 (probed), edge_index int64 (probed),
// output f32. Internal: GEMM/agg buffers bf16, math f32.
//
// R11: REVERT cooperative experiment (R10: 349->1339us; grid-sync + 4096-wave
// occupancy collapse). R9 structure + dispatch diet 17 -> 11 via:
//  (1) static bucket capacity CAP=18432 (=mu+16sigma of Binomial bucket count)
//      -> bcount/bscan die; CSR gets inter-bucket gaps; agg uses fill[w]
//      (== row end after fill2) instead of rowptr[w+1].
//  (2) k_deg2: dinv + rowptr + fill from bucket static base + intra-bucket
//      LDS scan (scan1/2/3 die).
//  (3) detect folded into k_prep (W blocks self-probe isbf); prep also zeroes
//      stats1/2 and seeds tail.
//  (4) bn_stats 512 -> 256 blocks (halves per-address atomic contention).
//
// ws layout (bytes):
//   [0       .. +200000)   dinv f32[NN]
//   [200704  .. +8)        flags: [0]=int64?, [1]=bf16-floats?
//   [201728  .. +1024)     stats1 (sum[128], sumsq[128])
//   [202752  .. +1024)     stats2
//   [404800  .. +200000)   rowptr int[NN] (row starts, gapped CSR)
//   [604816  .. +200000)   fill  int[NN]  (cursor; == row end after fill2)
//   [805632  .. +256)      tail int[64]
//   [1048576 .. +3.7MB)    csr_src int[49*CAP]
//   [4718592 .. +12.8MB)   hbuf  bf16[NN*DD] packed-slot layout (dinv-scaled)
//   [17518592.. +32768)    wp1 bf16[128*128] swizzled
//   [17551360.. +32768)    wp2 bf16[128*128] swizzled
//   [30056448.. +12.8MB)   aggbuf bf16[NN*DD] row-major
//   [42856448.. +7.3MB)    binned uint2[49*CAP]

typedef __hip_bfloat16 bf16;
typedef __attribute__((ext_vector_type(8))) short short8;   // 8 bf16 = 4 VGPR
typedef __attribute__((ext_vector_type(4))) float f32x4;    // MFMA accumulator

#define NN 50000
#define NE 800000
#define DD 128
#define BN_EPS 1e-5f
#define BIN_CHUNK 3125   // NE / 256 exactly
#define CAP 18432        // per-bucket slot capacity (72 * 256)
#define NBKT 49          // ceil(50000 / 1024)

__device__ __forceinline__ float b2f(bf16 v) { return __bfloat162float(v); }
__device__ __forceinline__ float ldf(const void* p, size_t idx, int isbf) {
  return isbf ? b2f(((const bf16*)p)[idx]) : ((const float*)p)[idx];
}
__device__ __forceinline__ int lde(const void* ei, size_t idx, int is64) {
  return is64 ? (int)((const long long*)ei)[idx] : ((const int*)ei)[idx];
}
__device__ __forceinline__ unsigned int f2bs(float v) {
  bf16 b = __float2bfloat16(v);
  return (unsigned int)*reinterpret_cast<unsigned short*>(&b);
}
__device__ __forceinline__ float bslo(unsigned int u) { return __uint_as_float(u << 16); }
__device__ __forceinline__ float bshi(unsigned int u) { return __uint_as_float(u & 0xFFFF0000u); }
__device__ __forceinline__ float s2f(short v) {
  return __uint_as_float(((unsigned int)(unsigned short)v) << 16);
}

// 129 blocks x 256. Blocks 0..63: swizzle W1; 64..127: swizzle W2 (self-probed
// isbf). Block 128: dtype flags, zero stats1/stats2, seed tail[b] = b*CAP.
__global__ __launch_bounds__(256) void k_prep(const int* ei, const unsigned short* x16,
                                              const void* W1, const void* W2,
                                              unsigned short* wp1, unsigned short* wp2,
                                              int* flags, float* stats1, float* stats2,
                                              int* tail) {
  const int tid = threadIdx.x;
  if (blockIdx.x == 128) {
    if (tid < 64) {
      unsigned long long m1 = __ballot(ei[2 * tid + 1] != 0);
      int ex = (x16[2 * tid] >> 7) & 0xFF;
      unsigned long long m2 = __ballot(ex >= 90 && ex <= 140);
      if (tid == 0) {
        flags[0] = (m1 == 0ull) ? 1 : 0;
        flags[1] = (__popcll(m2) >= 48) ? 1 : 0;
      }
      tail[tid] = tid * CAP;
    }
    stats1[tid] = 0.f;
    stats2[tid] = 0.f;
    return;
  }
  __shared__ int sbf;
  if (tid < 64) {
    int ex = (x16[2 * tid] >> 7) & 0xFF;
    unsigned long long m2 = __ballot(ex >= 90 && ex <= 140);
    if (tid == 0) sbf = (__popcll(m2) >= 48) ? 1 : 0;
  }
  __syncthreads();
  const int isbf = sbf;
  const void* W = blockIdx.x < 64 ? W1 : W2;
  unsigned short* wp = blockIdx.x < 64 ? wp1 : wp2;
  int idx = (blockIdx.x & 63) * 256 + tid;
  int k = idx >> 7, n = idx & 127;
  wp[(k >> 3) * 1024 + n * 8 + (k & 7)] = (unsigned short)f2bs(ldf(W, idx, isbf));
}

// Bin edges by dst-bucket (d>>10) into binned[] at statically-based slots.
__global__ __launch_bounds__(256) void k_bin(const void* ei, const int* flags,
                                             int* tail, uint2* binned) {
  __shared__ int cnt[64], cur[64], gb[64];
  const int is64 = flags[0];
  const int tid = threadIdx.x;
  const int e0 = blockIdx.x * BIN_CHUNK;
  if (tid < 64) { cnt[tid] = 0; cur[tid] = 0; }
  __syncthreads();
  for (int t = tid; t < BIN_CHUNK; t += 256) {
    int d = lde(ei, (size_t)NE + e0 + t, is64);
    atomicAdd(&cnt[d >> 10], 1);
  }
  __syncthreads();
  if (tid < 64 && cnt[tid] > 0) gb[tid] = atomicAdd(&tail[tid], cnt[tid]);
  __syncthreads();
  for (int t = tid; t < BIN_CHUNK; t += 256) {
    int s = lde(ei, (size_t)(e0 + t), is64);
    int d = lde(ei, (size_t)NE + e0 + t, is64);
    int b = d >> 10;
    int r = atomicAdd(&cur[b], 1);
    binned[gb[b] + r] = make_uint2((unsigned)s, (unsigned)d);
  }
}

// Per-bucket degree hist (LDS) -> dinv; rowptr/fill = bucket static base +
// intra-bucket exclusive prefix (binned is bucket-contiguous). 49 x 1024.
__global__ __launch_bounds__(1024) void k_deg2(const uint2* binned, const int* tail,
                                               float* dinv, int* rowptr, int* fill) {
  __shared__ int hist[1024];
  const int b = blockIdx.x;
  const int t = threadIdx.x;
  hist[t] = 0;
  __syncthreads();
  const int eb = b * CAP, ee = tail[b];
  for (int e = eb + t; e < ee; e += 1024) atomicAdd(&hist[binned[e].y & 1023], 1);
  __syncthreads();
  int h = hist[t];
  __syncthreads();
  for (int off = 1; off < 1024; off <<= 1) {
    int u = (t >= off) ? hist[t - off] : 0;
    __syncthreads();
    hist[t] += u;
    __syncthreads();
  }
  int node = b * 1024 + t;
  if (node < NN) {
    int start = eb + hist[t] - h;  // exclusive prefix
    rowptr[node] = start;
    fill[node] = start;
    dinv[node] = rsqrtf((float)(h + 1));  // +1 self-loop
  }
}

// Exact CSR fill inside L2-resident dst windows. block -> (bucket, chunk).
__global__ __launch_bounds__(256) void k_fill2(const uint2* binned, const int* tail,
                                               int* fill, int* csr_src) {
  const int b = blockIdx.x / 72;
  const int e = b * CAP + (blockIdx.x % 72) * 256 + threadIdx.x;
  if (e >= tail[b]) return;
  uint2 u = binned[e];
  int pos = atomicAdd(&fill[u.y], 1);
  csr_src[pos] = (int)u.x;
}

// MFMA GEMM. out = dinv-prescaled bf16 in packed-slot layout.
template <int XMODE>
__global__ __launch_bounds__(256) void k_gemm(const void* in_, const unsigned short* wp,
                                              const int* flags, const float* dinv,
                                              const float* stats, const void* g,
                                              const void* be, const void* al,
                                              unsigned int* out) {
  __shared__ alignas(16) short sW[16 * 128 * 8];  // 32 KB
  __shared__ float sSc[DD], sSh[DD], sAl;
  const int isbf = flags[1];
  const int tid = threadIdx.x;

  {
    const short8* src = (const short8*)wp;
    short8* dst = (short8*)sW;
#pragma unroll
    for (int i = 0; i < 8; i++) dst[tid + i * 256] = src[tid + i * 256];
  }
  if (XMODE == 2) {
    if (tid < DD) {
      const float inv_n = 1.0f / NN;
      float mu = stats[tid] * inv_n;
      float var = stats[DD + tid] * inv_n - mu * mu;
      float sc = rsqrtf(var + BN_EPS) * ldf(g, tid, isbf);
      sSc[tid] = sc;
      sSh[tid] = ldf(be, tid, isbf) - mu * sc;
    }
    if (tid == 0) sAl = ldf(al, 0, isbf);
  }
  __syncthreads();

  const int wave = tid >> 6;
  const int lane = tid & 63;
  const int quad = lane >> 4;
  const int m16 = lane & 15;
  const int r0 = blockIdx.x * 128 + wave * 32;

  f32x4 acc[2][8];
#pragma unroll
  for (int t = 0; t < 2; t++)
#pragma unroll
    for (int n = 0; n < 8; n++) acc[t][n] = (f32x4){0.f, 0.f, 0.f, 0.f};

#pragma unroll
  for (int q = 0; q < 4; q++) {
    const int kq = q * 32 + quad * 8;
    short8 af[2];
#pragma unroll
    for (int t = 0; t < 2; t++) {
      int row = r0 + t * 16 + m16;
      row = row < NN ? row : NN - 1;  // clamp; garbage rows never stored
      if (XMODE == 2) {
        short8 raw = *(const short8*)((const short*)in_ + (size_t)row * DD + kq);
        short8 f;
#pragma unroll
        for (int jj = 0; jj < 8; jj++) {
          float y = s2f(raw[jj]);
          y = y * sSc[kq + jj] + sSh[kq + jj];
          y = y > 0.f ? y : sAl * y;
          f[jj] = (short)f2bs(y);
        }
        af[t] = f;
      } else if (isbf) {
        af[t] = *(const short8*)((const short*)in_ + (size_t)row * DD + kq);
      } else {
        const float* ap = (const float*)in_ + (size_t)row * DD + kq;
        const float4 u0 = *(const float4*)ap;
        const float4 u1 = *(const float4*)(ap + 4);
        float v[8] = {u0.x, u0.y, u0.z, u0.w, u1.x, u1.y, u1.z, u1.w};
        short8 f;
#pragma unroll
        for (int jj = 0; jj < 8; jj++) f[jj] = (short)f2bs(v[jj]);
        af[t] = f;
      }
    }
    const int c = q * 4 + quad;
    const short* bp = sW + c * 1024 + m16 * 8;
#pragma unroll
    for (int n = 0; n < 8; n++) {
      const short8 bfrag = *(const short8*)(bp + n * 128);
      acc[0][n] = __builtin_amdgcn_mfma_f32_16x16x32_bf16(af[0], bfrag, acc[0][n], 0, 0, 0);
      acc[1][n] = __builtin_amdgcn_mfma_f32_16x16x32_bf16(af[1], bfrag, acc[1][n], 0, 0, 0);
    }
  }

#pragma unroll
  for (int t = 0; t < 2; t++)
#pragma unroll
    for (int r = 0; r < 4; r++) {
      int row = r0 + t * 16 + quad * 4 + r;
      if (row < NN) {
        float di = dinv[row];
        unsigned int* orow = out + (size_t)row * 64;
#pragma unroll
        for (int n = 0; n < 4; n++) {
          unsigned int p = (f2bs(di * acc[t][n + 4][r]) << 16) | f2bs(di * acc[t][n][r]);
          orow[n * 16 + m16] = p;
        }
      }
    }
}

// One wave per node (12500 blocks = 50000 waves, max TLP). Row range =
// [rowptr[w], fill[w]) in the gapped CSR. 8-deep gather unroll.
__global__ __launch_bounds__(256) void k_agg2(const unsigned int* hs, const float* dinv,
                                              const int* rowptr, const int* fillend,
                                              const int* csr_src, const void* bias,
                                              const int* flags, unsigned short* out) {
  int w = (blockIdx.x * 256 + threadIdx.x) >> 6;
  if (w >= NN) return;
  int lane = threadIdx.x & 63;
  float dd_ = dinv[w];
  unsigned int hv = hs[(size_t)w * 64 + lane];
  float ax = bslo(hv), ay = bshi(hv);
  int e = rowptr[w], e1 = fillend[w];
  for (; e + 7 < e1; e += 8) {
    int s0 = csr_src[e], s1 = csr_src[e + 1], s2 = csr_src[e + 2], s3 = csr_src[e + 3];
    int s4 = csr_src[e + 4], s5 = csr_src[e + 5], s6 = csr_src[e + 6], s7 = csr_src[e + 7];
    unsigned int v0 = hs[(size_t)s0 * 64 + lane];
    unsigned int v1 = hs[(size_t)s1 * 64 + lane];
    unsigned int v2 = hs[(size_t)s2 * 64 + lane];
    unsigned int v3 = hs[(size_t)s3 * 64 + lane];
    unsigned int v4 = hs[(size_t)s4 * 64 + lane];
    unsigned int v5 = hs[(size_t)s5 * 64 + lane];
    unsigned int v6 = hs[(size_t)s6 * 64 + lane];
    unsigned int v7 = hs[(size_t)s7 * 64 + lane];
    ax += bslo(v0) + bslo(v1) + bslo(v2) + bslo(v3) + bslo(v4) + bslo(v5) + bslo(v6) + bslo(v7);
    ay += bshi(v0) + bshi(v1) + bshi(v2) + bshi(v3) + bshi(v4) + bshi(v5) + bshi(v6) + bshi(v7);
  }
  for (; e + 3 < e1; e += 4) {
    int s0 = csr_src[e], s1 = csr_src[e + 1], s2 = csr_src[e + 2], s3 = csr_src[e + 3];
    unsigned int v0 = hs[(size_t)s0 * 64 + lane];
    unsigned int v1 = hs[(size_t)s1 * 64 + lane];
    unsigned int v2 = hs[(size_t)s2 * 64 + lane];
    unsigned int v3 = hs[(size_t)s3 * 64 + lane];
    ax += bslo(v0) + bslo(v1) + bslo(v2) + bslo(v3);
    ay += bshi(v0) + bshi(v1) + bshi(v2) + bshi(v3);
  }
  for (; e < e1; e++) {
    unsigned int v0 = hs[(size_t)csr_src[e] * 64 + lane];
    ax += bslo(v0);
    ay += bshi(v0);
  }
  int isbf = flags[1];
  unsigned short* orow = out + (size_t)w * DD;
  orow[lane] = (unsigned short)f2bs(dd_ * ax + ldf(bias, lane, isbf));
  orow[lane + 64] = (unsigned short)f2bs(dd_ * ay + ldf(bias, lane + 64, isbf));
}

// BN stats over bf16 row-major x: 256 blocks (contention = 256/address).
__global__ __launch_bounds__(256) void k_bn_stats(const unsigned int* x32, float* stats) {
  __shared__ float rsx[256], rsy[256], rqx[256], rqy[256];
  int t = threadIdx.x;
  int c = t & 63;
  float sx = 0.f, sy = 0.f, qx = 0.f, qy = 0.f;
  for (int r = blockIdx.x * 4 + (t >> 6); r < NN; r += gridDim.x * 4) {
    unsigned int u = x32[(size_t)r * 64 + c];
    float a = bslo(u), b = bshi(u);
    sx += a; qx += a * a;
    sy += b; qy += b * b;
  }
  rsx[t] = sx; rsy[t] = sy; rqx[t] = qx; rqy[t] = qy;
  __syncthreads();
  if (t < 64) {
    sx = rsx[t] + rsx[t + 64] + rsx[t + 128] + rsx[t + 192];
    sy = rsy[t] + rsy[t + 64] + rsy[t + 128] + rsy[t + 192];
    qx = rqx[t] + rqx[t + 64] + rqx[t + 128] + rqx[t + 192];
    qy = rqy[t] + rqy[t + 64] + rqy[t + 128] + rqy[t + 192];
    atomicAdd(&stats[2 * t], sx);
    atomicAdd(&stats[2 * t + 1], sy);
    atomicAdd(&stats[DD + 2 * t], qx);
    atomicAdd(&stats[DD + 2 * t + 1], qy);
  }
}

// Final BN+PReLU: bf16 row-major in -> d_out (f32 unless inputs were bf16).
__global__ __launch_bounds__(256) void k_bn_apply(const unsigned int* x32, const float* stats,
                                                  const void* g, const void* be, const void* al,
                                                  const int* flags, void* out) {
  int i4 = blockIdx.x * 256 + threadIdx.x;  // uint2 (4 cols) granularity
  if (i4 >= NN * 32) return;
  int isbf = flags[1];
  int jq = (i4 & 31) * 4;
  const float inv_n = 1.0f / NN;
  float alpha = ldf(al, 0, isbf);
  const uint2 xv = ((const uint2*)x32)[i4];
  float xa[4] = {bslo(xv.x), bshi(xv.x), bslo(xv.y), bshi(xv.y)};
  float y[4];
#pragma unroll
  for (int u = 0; u < 4; u++) {
    int j = jq + u;
    float mu = stats[j] * inv_n;
    float var = stats[DD + j] * inv_n - mu * mu;
    float sc = rsqrtf(var + BN_EPS) * ldf(g, j, isbf);
    float v = (xa[u] - mu) * sc + ldf(be, j, isbf);
    y[u] = v > 0.f ? v : alpha * v;
  }
  if (isbf) {
    uint2 o;
    o.x = (f2bs(y[1]) << 16) | f2bs(y[0]);
    o.y = (f2bs(y[3]) << 16) | f2bs(y[2]);
    ((uint2*)out)[i4] = o;
  } else {
    float4 o = {y[0], y[1], y[2], y[3]};
    ((float4*)out)[i4] = o;
  }
}

extern "C" void kernel_launch(void* const* d_in, const int* in_sizes, int n_in,
                              void* d_out, int out_size, void* d_ws, size_t ws_size,
                              hipStream_t stream) {
  const void* x = d_in[0];
  const int* ei = (const int*)d_in[1];
  const void* W1 = d_in[2];
  const void* b1 = d_in[3];
  const void* g1 = d_in[4];
  const void* be1 = d_in[5];
  const void* a1 = d_in[6];
  const void* W2 = d_in[7];
  const void* b2 = d_in[8];
  const void* g2 = d_in[9];
  const void* be2 = d_in[10];
  const void* a2 = d_in[11];

  char* w = (char*)d_ws;
  float* dinv = (float*)w;                              // 200000
  int* flags = (int*)(w + 200704);                      // 8
  float* stats1 = (float*)(w + 201728);                 // 1024
  float* stats2 = (float*)(w + 202752);                 // 1024
  int* rowptr = (int*)(w + 404800);                     // 200000
  int* fill = (int*)(w + 604816);                       // 200000
  int* tail = (int*)(w + 805632);                       // 256
  int* csr_src = (int*)(w + 1048576);                   // 3612672
  unsigned int* hbuf = (unsigned int*)(w + 4718592);    // 12800000
  unsigned short* wp1 = (unsigned short*)(w + 17518592);   // 32768
  unsigned short* wp2 = (unsigned short*)(w + 17551360);   // 32768
  unsigned short* aggbuf = (unsigned short*)(w + 30056448);  // 12800000
  uint2* binned = (uint2*)(w + 42856448);               // 7225344

  const int NB_G = (NN + 127) / 128;   // 391
  const int NB_V = NN * 32 / 256;      // 6250
  const int NB_W = NN * 64 / 256;      // 12500

  k_prep<<<dim3(129), dim3(256), 0, stream>>>(ei, (const unsigned short*)x, W1, W2,
                                              wp1, wp2, flags, stats1, stats2, tail);
  k_bin<<<dim3(256), dim3(256), 0, stream>>>(ei, flags, tail, binned);
  k_deg2<<<dim3(NBKT), dim3(1024), 0, stream>>>(binned, tail, dinv, rowptr, fill);
  k_fill2<<<dim3(NBKT * 72), dim3(256), 0, stream>>>(binned, tail, fill, csr_src);

  // ---- layer 1 ----
  k_gemm<0><<<dim3(NB_G), dim3(256), 0, stream>>>(x, wp1, flags, dinv,
                                                  nullptr, nullptr, nullptr, nullptr, hbuf);
  k_agg2<<<dim3(NB_W), dim3(256), 0, stream>>>(hbuf, dinv, rowptr, fill, csr_src, b1,
                                               flags, aggbuf);
  k_bn_stats<<<dim3(256), dim3(256), 0, stream>>>((const unsigned int*)aggbuf, stats1);

  // ---- layer 2 (BN1+PReLU fused into GEMM A-path) ----
  k_gemm<2><<<dim3(NB_G), dim3(256), 0, stream>>>(aggbuf, wp2, flags, dinv,
                                                  stats1, g1, be1, a1, hbuf);
  k_agg2<<<dim3(NB_W), dim3(256), 0, stream>>>(hbuf, dinv, rowptr, fill, csr_src, b2,
                                               flags, aggbuf);
  k_bn_stats<<<dim3(256), dim3(256), 0, stream>>>((const unsigned int*)aggbuf, stats2);
  k_bn_apply<<<dim3(NB_V), dim3(256), 0, stream>>>((const unsigned int*)aggbuf, stats2,
                                                   g2, be2, a2, flags, d_out);
}

// Round 12
// 277.148 us; speedup vs baseline: 4.8297x; 1.1368x over previous
//
#include <hip/hip_runtime.h>
#include <hip/hip_bf16.h>

// 2-layer GCN encoder: (GCNConv -> BatchNorm1d(train) -> PReLU) x 2
// N=50000, E=800000, D=128. Inputs f32 (probed), edge_index int64 (probed),
// output f32. Internal: GEMM/agg buffers bf16, math f32.
//
// R12 (9 dispatches, from 11):
//  (1) k_deg2 + k_fill2 merged: bucket block converts its LDS histogram into
//      LDS cursors and fills csr_src in-kernel (LDS atomics, no fill[] array;
//      rowend[] stored directly).
//  (2) layer-1 BN stats folded into k_agg1: per-block LDS reduce ->
//      64-copy partials (stats1p); k_gemm2 prologue sums the copies.
//      Layer-2 keeps its bn_stats kernel (its consumer is 6250 blocks wide).
//  (3) k_bin single-pass: edges staged in LDS (25KB) during count pass.
//
// ws layout (bytes):
//   [0       .. +200000)   dinv f32[NN]
//   [200704  .. +8)        flags: [0]=int64?, [1]=bf16-floats?
//   [202752  .. +1024)     stats2 (sum[128], sumsq[128])
//   [404800  .. +200000)   rowptr int[NN] (row starts, gapped CSR)
//   [604816  .. +200000)   rowend int[NN]
//   [805632  .. +256)      tail int[64]
//   [806400  .. +65536)    stats1p f32[64][256] (per-copy: sum[128],sumsq[128])
//   [1048576 .. +3.7MB)    csr_src int[49*CAP]
//   [4718592 .. +12.8MB)   hbuf  bf16[NN*DD] packed-slot layout (dinv-scaled)
//   [17518592.. +32768)    wp1 bf16[128*128] swizzled
//   [17551360.. +32768)    wp2 bf16[128*128] swizzled
//   [30056448.. +12.8MB)   aggbuf bf16[NN*DD] row-major
//   [42856448.. +7.3MB)    binned uint2[49*CAP]

typedef __hip_bfloat16 bf16;
typedef __attribute__((ext_vector_type(8))) short short8;   // 8 bf16 = 4 VGPR
typedef __attribute__((ext_vector_type(4))) float f32x4;    // MFMA accumulator

#define NN 50000
#define NE 800000
#define DD 128
#define BN_EPS 1e-5f
#define BIN_CHUNK 3125   // NE / 256 exactly
#define CAP 18432        // per-bucket slot capacity (72 * 256)
#define NBKT 49          // ceil(50000 / 1024)

__device__ __forceinline__ float b2f(bf16 v) { return __bfloat162float(v); }
__device__ __forceinline__ float ldf(const void* p, size_t idx, int isbf) {
  return isbf ? b2f(((const bf16*)p)[idx]) : ((const float*)p)[idx];
}
__device__ __forceinline__ int lde(const void* ei, size_t idx, int is64) {
  return is64 ? (int)((const long long*)ei)[idx] : ((const int*)ei)[idx];
}
__device__ __forceinline__ unsigned int f2bs(float v) {
  bf16 b = __float2bfloat16(v);
  return (unsigned int)*reinterpret_cast<unsigned short*>(&b);
}
__device__ __forceinline__ float bslo(unsigned int u) { return __uint_as_float(u << 16); }
__device__ __forceinline__ float bshi(unsigned int u) { return __uint_as_float(u & 0xFFFF0000u); }
__device__ __forceinline__ float s2f(short v) {
  return __uint_as_float(((unsigned int)(unsigned short)v) << 16);
}

// 129 blocks x 256. Blocks 0..63: swizzle W1 + zero stats1p[copy=bid];
// 64..127: swizzle W2. Block 128: flags, tail seeds, stats2 zero.
__global__ __launch_bounds__(256) void k_prep(const int* ei, const unsigned short* x16,
                                              const void* W1, const void* W2,
                                              unsigned short* wp1, unsigned short* wp2,
                                              int* flags, float* stats1p, float* stats2,
                                              int* tail) {
  const int tid = threadIdx.x;
  if (blockIdx.x == 128) {
    if (tid < 64) {
      unsigned long long m1 = __ballot(ei[2 * tid + 1] != 0);
      int ex = (x16[2 * tid] >> 7) & 0xFF;
      unsigned long long m2 = __ballot(ex >= 90 && ex <= 140);
      if (tid == 0) {
        flags[0] = (m1 == 0ull) ? 1 : 0;
        flags[1] = (__popcll(m2) >= 48) ? 1 : 0;
      }
      tail[tid] = tid * CAP;
    }
    stats2[tid] = 0.f;
    return;
  }
  if (blockIdx.x < 64) stats1p[blockIdx.x * 256 + tid] = 0.f;
  __shared__ int sbf;
  if (tid < 64) {
    int ex = (x16[2 * tid] >> 7) & 0xFF;
    unsigned long long m2 = __ballot(ex >= 90 && ex <= 140);
    if (tid == 0) sbf = (__popcll(m2) >= 48) ? 1 : 0;
  }
  __syncthreads();
  const int isbf = sbf;
  const void* W = blockIdx.x < 64 ? W1 : W2;
  unsigned short* wp = blockIdx.x < 64 ? wp1 : wp2;
  int idx = (blockIdx.x & 63) * 256 + tid;
  int k = idx >> 7, n = idx & 127;
  wp[(k >> 3) * 1024 + n * 8 + (k & 7)] = (unsigned short)f2bs(ldf(W, idx, isbf));
}

// Bin edges by dst-bucket (d>>10) into binned[]; single global pass (edges
// staged in LDS), per-block reserved segments -> L2-coalesced writes.
__global__ __launch_bounds__(256) void k_bin(const void* ei, const int* flags,
                                             int* tail, uint2* binned) {
  __shared__ int cnt[64], cur[64], gb[64];
  __shared__ uint2 ebuf[BIN_CHUNK];  // 25000 B
  const int is64 = flags[0];
  const int tid = threadIdx.x;
  const int e0 = blockIdx.x * BIN_CHUNK;
  if (tid < 64) { cnt[tid] = 0; cur[tid] = 0; }
  __syncthreads();
  for (int t = tid; t < BIN_CHUNK; t += 256) {
    int s = lde(ei, (size_t)(e0 + t), is64);
    int d = lde(ei, (size_t)NE + e0 + t, is64);
    ebuf[t] = make_uint2((unsigned)s, (unsigned)d);
    atomicAdd(&cnt[d >> 10], 1);
  }
  __syncthreads();
  if (tid < 64 && cnt[tid] > 0) gb[tid] = atomicAdd(&tail[tid], cnt[tid]);
  __syncthreads();
  for (int t = tid; t < BIN_CHUNK; t += 256) {
    uint2 u = ebuf[t];
    int b = (int)(u.y >> 10);
    int r = atomicAdd(&cur[b], 1);
    binned[gb[b] + r] = u;
  }
}

// Per-bucket: degree hist (LDS) -> dinv/rowptr/rowend, then exact CSR fill
// with LDS cursors (no global fill[], no L2 atomics). 49 blocks x 1024.
__global__ __launch_bounds__(1024) void k_degfill(const uint2* binned, const int* tail,
                                                  float* dinv, int* rowptr, int* rowend,
                                                  int* csr_src) {
  __shared__ int hist[1024];
  const int b = blockIdx.x;
  const int t = threadIdx.x;
  hist[t] = 0;
  __syncthreads();
  const int eb = b * CAP, ee = tail[b];
  for (int e = eb + t; e < ee; e += 1024) atomicAdd(&hist[binned[e].y & 1023], 1);
  __syncthreads();
  int h = hist[t];
  __syncthreads();
  for (int off = 1; off < 1024; off <<= 1) {  // inclusive scan
    int u = (t >= off) ? hist[t - off] : 0;
    __syncthreads();
    hist[t] += u;
    __syncthreads();
  }
  int start = eb + hist[t] - h;  // exclusive prefix, global position
  int node = b * 1024 + t;
  if (node < NN) {
    rowptr[node] = start;
    rowend[node] = start + h;
    dinv[node] = rsqrtf((float)(h + 1));  // +1 self-loop
  }
  __syncthreads();
  hist[t] = start;  // repurpose as fill cursor
  __syncthreads();
  for (int e = eb + t; e < ee; e += 1024) {
    uint2 u = binned[e];
    int pos = atomicAdd(&hist[u.y & 1023], 1);
    csr_src[pos] = (int)u.x;
  }
}

// MFMA GEMM. out = dinv-prescaled bf16 in packed-slot layout: row r, u32 slot
// s holds bf16 pair (col s, col s+64). W pre-swizzled (wp), raw LDS copy.
// XMODE 0: layer-1 input (probe f32/bf16). XMODE 2: aggbuf bf16 + fused BN1
// (stats from 64-copy partial array statsp).
template <int XMODE>
__global__ __launch_bounds__(256) void k_gemm(const void* in_, const unsigned short* wp,
                                              const int* flags, const float* dinv,
                                              const float* statsp, const void* g,
                                              const void* be, const void* al,
                                              unsigned int* out) {
  __shared__ alignas(16) short sW[16 * 128 * 8];  // 32 KB
  __shared__ float sSc[DD], sSh[DD], sAl;
  const int isbf = flags[1];
  const int tid = threadIdx.x;

  {
    const short8* src = (const short8*)wp;
    short8* dst = (short8*)sW;
#pragma unroll
    for (int i = 0; i < 8; i++) dst[tid + i * 256] = src[tid + i * 256];
  }
  if (XMODE == 2) {
    if (tid < DD) {
      float s = 0.f, q = 0.f;
#pragma unroll 8
      for (int k = 0; k < 64; k++) {
        s += statsp[k * 256 + tid];
        q += statsp[k * 256 + 128 + tid];
      }
      const float inv_n = 1.0f / NN;
      float mu = s * inv_n;
      float var = q * inv_n - mu * mu;
      float sc = rsqrtf(var + BN_EPS) * ldf(g, tid, isbf);
      sSc[tid] = sc;
      sSh[tid] = ldf(be, tid, isbf) - mu * sc;
    }
    if (tid == 0) sAl = ldf(al, 0, isbf);
  }
  __syncthreads();

  const int wave = tid >> 6;
  const int lane = tid & 63;
  const int quad = lane >> 4;
  const int m16 = lane & 15;
  const int r0 = blockIdx.x * 128 + wave * 32;

  f32x4 acc[2][8];
#pragma unroll
  for (int t = 0; t < 2; t++)
#pragma unroll
    for (int n = 0; n < 8; n++) acc[t][n] = (f32x4){0.f, 0.f, 0.f, 0.f};

#pragma unroll
  for (int q = 0; q < 4; q++) {
    const int kq = q * 32 + quad * 8;
    short8 af[2];
#pragma unroll
    for (int t = 0; t < 2; t++) {
      int row = r0 + t * 16 + m16;
      row = row < NN ? row : NN - 1;  // clamp; garbage rows never stored
      if (XMODE == 2) {
        short8 raw = *(const short8*)((const short*)in_ + (size_t)row * DD + kq);
        short8 f;
#pragma unroll
        for (int jj = 0; jj < 8; jj++) {
          float y = s2f(raw[jj]);
          y = y * sSc[kq + jj] + sSh[kq + jj];
          y = y > 0.f ? y : sAl * y;
          f[jj] = (short)f2bs(y);
        }
        af[t] = f;
      } else if (isbf) {
        af[t] = *(const short8*)((const short*)in_ + (size_t)row * DD + kq);
      } else {
        const float* ap = (const float*)in_ + (size_t)row * DD + kq;
        const float4 u0 = *(const float4*)ap;
        const float4 u1 = *(const float4*)(ap + 4);
        float v[8] = {u0.x, u0.y, u0.z, u0.w, u1.x, u1.y, u1.z, u1.w};
        short8 f;
#pragma unroll
        for (int jj = 0; jj < 8; jj++) f[jj] = (short)f2bs(v[jj]);
        af[t] = f;
      }
    }
    const int c = q * 4 + quad;
    const short* bp = sW + c * 1024 + m16 * 8;
#pragma unroll
    for (int n = 0; n < 8; n++) {
      const short8 bfrag = *(const short8*)(bp + n * 128);
      acc[0][n] = __builtin_amdgcn_mfma_f32_16x16x32_bf16(af[0], bfrag, acc[0][n], 0, 0, 0);
      acc[1][n] = __builtin_amdgcn_mfma_f32_16x16x32_bf16(af[1], bfrag, acc[1][n], 0, 0, 0);
    }
  }

#pragma unroll
  for (int t = 0; t < 2; t++)
#pragma unroll
    for (int r = 0; r < 4; r++) {
      int row = r0 + t * 16 + quad * 4 + r;
      if (row < NN) {
        float di = dinv[row];
        unsigned int* orow = out + (size_t)row * 64;
#pragma unroll
        for (int n = 0; n < 4; n++) {
          unsigned int p = (f2bs(di * acc[t][n + 4][r]) << 16) | f2bs(di * acc[t][n][r]);
          orow[n * 16 + m16] = p;
        }
      }
    }
}

// One wave per node (12500 blocks = 50000 waves exactly, max TLP). Row range
// [rowptr[w], rowend[w]) in the gapped CSR. 8-deep gather unroll.
// STATS: accumulate this block's 4 rows into stats1p[blockIdx&63] (layer 1).
template <bool STATS>
__global__ __launch_bounds__(256) void k_agg(const unsigned int* hs, const float* dinv,
                                             const int* rowptr, const int* rowend,
                                             const int* csr_src, const void* bias,
                                             const int* flags, unsigned short* out,
                                             float* statsp) {
  const int tid = threadIdx.x;
  int w = (blockIdx.x * 256 + tid) >> 6;   // never >= NN (12500*4 == NN)
  int lane = tid & 63;
  float dd_ = dinv[w];
  unsigned int hv = hs[(size_t)w * 64 + lane];
  float ax = bslo(hv), ay = bshi(hv);
  int e = rowptr[w], e1 = rowend[w];
  for (; e + 7 < e1; e += 8) {
    int s0 = csr_src[e], s1 = csr_src[e + 1], s2 = csr_src[e + 2], s3 = csr_src[e + 3];
    int s4 = csr_src[e + 4], s5 = csr_src[e + 5], s6 = csr_src[e + 6], s7 = csr_src[e + 7];
    unsigned int v0 = hs[(size_t)s0 * 64 + lane];
    unsigned int v1 = hs[(size_t)s1 * 64 + lane];
    unsigned int v2 = hs[(size_t)s2 * 64 + lane];
    unsigned int v3 = hs[(size_t)s3 * 64 + lane];
    unsigned int v4 = hs[(size_t)s4 * 64 + lane];
    unsigned int v5 = hs[(size_t)s5 * 64 + lane];
    unsigned int v6 = hs[(size_t)s6 * 64 + lane];
    unsigned int v7 = hs[(size_t)s7 * 64 + lane];
    ax += bslo(v0) + bslo(v1) + bslo(v2) + bslo(v3) + bslo(v4) + bslo(v5) + bslo(v6) + bslo(v7);
    ay += bshi(v0) + bshi(v1) + bshi(v2) + bshi(v3) + bshi(v4) + bshi(v5) + bshi(v6) + bshi(v7);
  }
  for (; e + 3 < e1; e += 4) {
    int s0 = csr_src[e], s1 = csr_src[e + 1], s2 = csr_src[e + 2], s3 = csr_src[e + 3];
    unsigned int v0 = hs[(size_t)s0 * 64 + lane];
    unsigned int v1 = hs[(size_t)s1 * 64 + lane];
    unsigned int v2 = hs[(size_t)s2 * 64 + lane];
    unsigned int v3 = hs[(size_t)s3 * 64 + lane];
    ax += bslo(v0) + bslo(v1) + bslo(v2) + bslo(v3);
    ay += bshi(v0) + bshi(v1) + bshi(v2) + bshi(v3);
  }
  for (; e < e1; e++) {
    unsigned int v0 = hs[(size_t)csr_src[e] * 64 + lane];
    ax += bslo(v0);
    ay += bshi(v0);
  }
  int isbf = flags[1];
  float o1 = dd_ * ax + ldf(bias, lane, isbf);
  float o2 = dd_ * ay + ldf(bias, lane + 64, isbf);
  unsigned short* orow = out + (size_t)w * DD;
  orow[lane] = (unsigned short)f2bs(o1);
  orow[lane + 64] = (unsigned short)f2bs(o2);

  if (STATS) {
    __shared__ float rs1[256], rq1[256], rs2[256], rq2[256];
    rs1[tid] = o1; rq1[tid] = o1 * o1;
    rs2[tid] = o2; rq2[tid] = o2 * o2;
    __syncthreads();
    float* p = statsp + (blockIdx.x & 63) * 256;
    if (tid < 64) {  // col tid (= lane of o1)
      float s = rs1[tid] + rs1[tid + 64] + rs1[tid + 128] + rs1[tid + 192];
      float q = rq1[tid] + rq1[tid + 64] + rq1[tid + 128] + rq1[tid + 192];
      atomicAdd(&p[tid], s);
      atomicAdd(&p[128 + tid], q);
    } else if (tid < 128) {  // col tid (= 64 + lane of o2)
      int l = tid - 64;
      float s = rs2[l] + rs2[l + 64] + rs2[l + 128] + rs2[l + 192];
      float q = rq2[l] + rq2[l + 64] + rq2[l + 128] + rq2[l + 192];
      atomicAdd(&p[tid], s);
      atomicAdd(&p[128 + tid], q);
    }
  }
}

// BN stats over bf16 row-major x (layer 2): 256 blocks.
__global__ __launch_bounds__(256) void k_bn_stats(const unsigned int* x32, float* stats) {
  __shared__ float rsx[256], rsy[256], rqx[256], rqy[256];
  int t = threadIdx.x;
  int c = t & 63;
  float sx = 0.f, sy = 0.f, qx = 0.f, qy = 0.f;
  for (int r = blockIdx.x * 4 + (t >> 6); r < NN; r += gridDim.x * 4) {
    unsigned int u = x32[(size_t)r * 64 + c];
    float a = bslo(u), b = bshi(u);
    sx += a; qx += a * a;
    sy += b; qy += b * b;
  }
  rsx[t] = sx; rsy[t] = sy; rqx[t] = qx; rqy[t] = qy;
  __syncthreads();
  if (t < 64) {
    sx = rsx[t] + rsx[t + 64] + rsx[t + 128] + rsx[t + 192];
    sy = rsy[t] + rsy[t + 64] + rsy[t + 128] + rsy[t + 192];
    qx = rqx[t] + rqx[t + 64] + rqx[t + 128] + rqx[t + 192];
    qy = rqy[t] + rqy[t + 64] + rqy[t + 128] + rqy[t + 192];
    atomicAdd(&stats[2 * t], sx);
    atomicAdd(&stats[2 * t + 1], sy);
    atomicAdd(&stats[DD + 2 * t], qx);
    atomicAdd(&stats[DD + 2 * t + 1], qy);
  }
}

// Final BN+PReLU: bf16 row-major in -> d_out (f32 unless inputs were bf16).
__global__ __launch_bounds__(256) void k_bn_apply(const unsigned int* x32, const float* stats,
                                                  const void* g, const void* be, const void* al,
                                                  const int* flags, void* out) {
  int i4 = blockIdx.x * 256 + threadIdx.x;  // uint2 (4 cols) granularity
  if (i4 >= NN * 32) return;
  int isbf = flags[1];
  int jq = (i4 & 31) * 4;
  const float inv_n = 1.0f / NN;
  float alpha = ldf(al, 0, isbf);
  const uint2 xv = ((const uint2*)x32)[i4];
  float xa[4] = {bslo(xv.x), bshi(xv.x), bslo(xv.y), bshi(xv.y)};
  float y[4];
#pragma unroll
  for (int u = 0; u < 4; u++) {
    int j = jq + u;
    float mu = stats[j] * inv_n;
    float var = stats[DD + j] * inv_n - mu * mu;
    float sc = rsqrtf(var + BN_EPS) * ldf(g, j, isbf);
    float v = (xa[u] - mu) * sc + ldf(be, j, isbf);
    y[u] = v > 0.f ? v : alpha * v;
  }
  if (isbf) {
    uint2 o;
    o.x = (f2bs(y[1]) << 16) | f2bs(y[0]);
    o.y = (f2bs(y[3]) << 16) | f2bs(y[2]);
    ((uint2*)out)[i4] = o;
  } else {
    float4 o = {y[0], y[1], y[2], y[3]};
    ((float4*)out)[i4] = o;
  }
}

extern "C" void kernel_launch(void* const* d_in, const int* in_sizes, int n_in,
                              void* d_out, int out_size, void* d_ws, size_t ws_size,
                              hipStream_t stream) {
  const void* x = d_in[0];
  const int* ei = (const int*)d_in[1];
  const void* W1 = d_in[2];
  const void* b1 = d_in[3];
  const void* g1 = d_in[4];
  const void* be1 = d_in[5];
  const void* a1 = d_in[6];
  const void* W2 = d_in[7];
  const void* b2 = d_in[8];
  const void* g2 = d_in[9];
  const void* be2 = d_in[10];
  const void* a2 = d_in[11];

  char* w = (char*)d_ws;
  float* dinv = (float*)w;                              // 200000
  int* flags = (int*)(w + 200704);                      // 8
  float* stats2 = (float*)(w + 202752);                 // 1024
  int* rowptr = (int*)(w + 404800);                     // 200000
  int* rowend = (int*)(w + 604816);                     // 200000
  int* tail = (int*)(w + 805632);                       // 256
  float* stats1p = (float*)(w + 806400);                // 65536
  int* csr_src = (int*)(w + 1048576);                   // 3612672
  unsigned int* hbuf = (unsigned int*)(w + 4718592);    // 12800000
  unsigned short* wp1 = (unsigned short*)(w + 17518592);   // 32768
  unsigned short* wp2 = (unsigned short*)(w + 17551360);   // 32768
  unsigned short* aggbuf = (unsigned short*)(w + 30056448);  // 12800000
  uint2* binned = (uint2*)(w + 42856448);               // 7225344

  const int NB_G = (NN + 127) / 128;   // 391
  const int NB_V = NN * 32 / 256;      // 6250
  const int NB_W = NN * 64 / 256;      // 12500

  k_prep<<<dim3(129), dim3(256), 0, stream>>>(ei, (const unsigned short*)x, W1, W2,
                                              wp1, wp2, flags, stats1p, stats2, tail);
  k_bin<<<dim3(256), dim3(256), 0, stream>>>(ei, flags, tail, binned);
  k_degfill<<<dim3(NBKT), dim3(1024), 0, stream>>>(binned, tail, dinv, rowptr, rowend,
                                                   csr_src);

  // ---- layer 1 ----
  k_gemm<0><<<dim3(NB_G), dim3(256), 0, stream>>>(x, wp1, flags, dinv,
                                                  nullptr, nullptr, nullptr, nullptr, hbuf);
  k_agg<true><<<dim3(NB_W), dim3(256), 0, stream>>>(hbuf, dinv, rowptr, rowend, csr_src,
                                                    b1, flags, aggbuf, stats1p);

  // ---- layer 2 (BN1+PReLU fused into GEMM A-path via stats1p) ----
  k_gemm<2><<<dim3(NB_G), dim3(256), 0, stream>>>(aggbuf, wp2, flags, dinv,
                                                  stats1p, g1, be1, a1, hbuf);
  k_agg<false><<<dim3(NB_W), dim3(256), 0, stream>>>(hbuf, dinv, rowptr, rowend, csr_src,
                                                     b2, flags, aggbuf, nullptr);
  k_bn_stats<<<dim3(256), dim3(256), 0, stream>>>((const unsigned int*)aggbuf, stats2);
  k_bn_apply<<<dim3(NB_V), dim3(256), 0, stream>>>((const unsigned int*)aggbuf, stats2,
                                                   g2, be2, a2, flags, d_out);
}

// Round 13
// 237.503 us; speedup vs baseline: 5.6358x; 1.1669x over previous
//
#include <hip/hip_runtime.h>
#include <hip/hip_bf16.h>

// 2-layer GCN encoder: (GCNConv -> BatchNorm1d(train) -> PReLU) x 2
// N=50000, E=800000, D=128. Inputs f32 (probed), edge_index int64 (probed),
// output f32. Internal: GEMM/agg buffers bf16, math f32.
//
// R13 (7 kernels + 1 tiny memset, from 9 kernels):
//  (1) k_prep killed: k_bin self-probes dtypes, blocks 0..127 swizzle W1/W2,
//      block 0 publishes flags; tailc zero-based (256B hipMemsetAsync).
//  (2) layer-2 stats now partials too (k_agg always accumulates stats2p);
//      k_bn_stats dies; k_bn_apply = 1024 grid-stride blocks, prologue sums
//      the 64 copies into LDS sc/sh (also kills per-element rsqrt recompute).
//  (3) binned[] packed to 32 bits: (s<<16)|(bucket<<10)|(d&1023) -> halves
//      bin write + degfill's two read passes; ebuf LDS 25 -> 12.5 KB.
//  (4) stats1p/stats2p zeroing folded into gemm0/gemm2 prologues.
//
// ws layout (bytes):
//   [0       .. +200000)   dinv f32[NN]
//   [200704  .. +8)        flags: [0]=int64?, [1]=bf16-floats?
//   [404800  .. +200000)   rowptr int[NN] (row starts, gapped CSR)
//   [604816  .. +200000)   rowend int[NN]
//   [805632  .. +256)      tailc int[64] (zeroed by memset; bucket fill counts)
//   [806400  .. +65536)    stats1p f32[64][256]
//   [871936  .. +65536)    stats2p f32[64][256]
//   [1048576 .. +3.7MB)    csr_src int[49*CAP]
//   [4718592 .. +12.8MB)   hbuf  bf16[NN*DD] packed-slot layout (dinv-scaled)
//   [17518592.. +32768)    wp1 bf16[128*128] swizzled
//   [17551360.. +32768)    wp2 bf16[128*128] swizzled
//   [30056448.. +12.8MB)   aggbuf bf16[NN*DD] row-major
//   [42856448.. +3.7MB)    binned uint[49*CAP] packed

typedef __hip_bfloat16 bf16;
typedef __attribute__((ext_vector_type(8))) short short8;   // 8 bf16 = 4 VGPR
typedef __attribute__((ext_vector_type(4))) float f32x4;    // MFMA accumulator

#define NN 50000
#define NE 800000
#define DD 128
#define BN_EPS 1e-5f
#define BIN_CHUNK 3125   // NE / 256 exactly
#define CAP 18432        // per-bucket slot capacity (72*256; mu+16sigma)
#define NBKT 49          // ceil(50000 / 1024)

__device__ __forceinline__ float b2f(bf16 v) { return __bfloat162float(v); }
__device__ __forceinline__ float ldf(const void* p, size_t idx, int isbf) {
  return isbf ? b2f(((const bf16*)p)[idx]) : ((const float*)p)[idx];
}
__device__ __forceinline__ int lde(const void* ei, size_t idx, int is64) {
  return is64 ? (int)((const long long*)ei)[idx] : ((const int*)ei)[idx];
}
__device__ __forceinline__ unsigned int f2bs(float v) {
  bf16 b = __float2bfloat16(v);
  return (unsigned int)*reinterpret_cast<unsigned short*>(&b);
}
__device__ __forceinline__ float bslo(unsigned int u) { return __uint_as_float(u << 16); }
__device__ __forceinline__ float bshi(unsigned int u) { return __uint_as_float(u & 0xFFFF0000u); }
__device__ __forceinline__ float s2f(short v) {
  return __uint_as_float(((unsigned int)(unsigned short)v) << 16);
}

// 256 blocks x 256. Per-block dtype self-probe; block 0 publishes flags;
// blocks 0..63 swizzle W1, 64..127 swizzle W2; all bin their edge chunk into
// packed binned[] at zero-based bucket counters (tailc pre-zeroed).
__global__ __launch_bounds__(256) void k_bin(const int* ei_i, const unsigned short* x16,
                                             const void* W1, const void* W2,
                                             unsigned short* wp1, unsigned short* wp2,
                                             int* flags, int* tailc, unsigned int* binned) {
  __shared__ int cnt[64], cur[64], gb[64], sflags[2];
  __shared__ unsigned int ebuf[BIN_CHUNK];  // 12.5 KB
  const int tid = threadIdx.x;
  const int bid = blockIdx.x;
  if (tid < 64) {
    unsigned long long m1 = __ballot(ei_i[2 * tid + 1] != 0);
    int ex = (x16[2 * tid] >> 7) & 0xFF;
    unsigned long long m2 = __ballot(ex >= 90 && ex <= 140);
    if (tid == 0) {
      sflags[0] = (m1 == 0ull) ? 1 : 0;
      sflags[1] = (__popcll(m2) >= 48) ? 1 : 0;
    }
    cnt[tid] = 0;
    cur[tid] = 0;
  }
  __syncthreads();
  const int is64 = sflags[0], isbf = sflags[1];
  if (bid == 0 && tid == 0) { flags[0] = is64; flags[1] = isbf; }
  if (bid < 128) {  // W swizzle side-job
    const void* W = bid < 64 ? W1 : W2;
    unsigned short* wp = bid < 64 ? wp1 : wp2;
    int idx = (bid & 63) * 256 + tid;
    int k = idx >> 7, n = idx & 127;
    wp[(k >> 3) * 1024 + n * 8 + (k & 7)] = (unsigned short)f2bs(ldf(W, idx, isbf));
  }
  const void* ei = (const void*)ei_i;
  const int e0 = bid * BIN_CHUNK;
  for (int t = tid; t < BIN_CHUNK; t += 256) {
    int s = lde(ei, (size_t)(e0 + t), is64);
    int d = lde(ei, (size_t)NE + e0 + t, is64);
    ebuf[t] = ((unsigned)s << 16) | ((unsigned)(d >> 10) << 10) | (unsigned)(d & 1023);
    atomicAdd(&cnt[d >> 10], 1);
  }
  __syncthreads();
  if (tid < 64 && cnt[tid] > 0) gb[tid] = tid * CAP + atomicAdd(&tailc[tid], cnt[tid]);
  __syncthreads();
  for (int t = tid; t < BIN_CHUNK; t += 256) {
    unsigned int u = ebuf[t];
    int b = (int)((u >> 10) & 63);
    int r = atomicAdd(&cur[b], 1);
    binned[gb[b] + r] = u;
  }
}

// Per-bucket: degree hist (LDS) -> dinv/rowptr/rowend, then exact CSR fill
// with LDS cursors. 49 blocks x 1024. packed u: s=u>>16, dlow=u&1023.
__global__ __launch_bounds__(1024) void k_degfill(const unsigned int* binned, const int* tailc,
                                                  float* dinv, int* rowptr, int* rowend,
                                                  int* csr_src) {
  __shared__ int hist[1024];
  const int b = blockIdx.x;
  const int t = threadIdx.x;
  hist[t] = 0;
  __syncthreads();
  const int eb = b * CAP, ee = eb + tailc[b];
  for (int e = eb + t; e < ee; e += 1024) atomicAdd(&hist[binned[e] & 1023], 1);
  __syncthreads();
  int h = hist[t];
  __syncthreads();
  for (int off = 1; off < 1024; off <<= 1) {  // inclusive scan
    int u = (t >= off) ? hist[t - off] : 0;
    __syncthreads();
    hist[t] += u;
    __syncthreads();
  }
  int start = eb + hist[t] - h;  // exclusive prefix, global position
  int node = b * 1024 + t;
  if (node < NN) {
    rowptr[node] = start;
    rowend[node] = start + h;
    dinv[node] = rsqrtf((float)(h + 1));  // +1 self-loop
  }
  __syncthreads();
  hist[t] = start;  // repurpose as fill cursor
  __syncthreads();
  for (int e = eb + t; e < ee; e += 1024) {
    unsigned int u = binned[e];
    int pos = atomicAdd(&hist[u & 1023], 1);
    csr_src[pos] = (int)(u >> 16);
  }
}

// MFMA GEMM. out = dinv-prescaled bf16 in packed-slot layout: row r, u32 slot
// s holds bf16 pair (col s, col s+64). W pre-swizzled (wp), raw LDS copy.
// XMODE 0: layer-1 input (probe f32/bf16). XMODE 2: aggbuf bf16 + fused BN1
// (stats from 64-copy partials statsp). Blocks 0..63 zero zstats (consumed by
// the NEXT kernel's atomics -- stream-ordered, safe).
template <int XMODE>
__global__ __launch_bounds__(256) void k_gemm(const void* in_, const unsigned short* wp,
                                              const int* flags, const float* dinv,
                                              const float* statsp, const void* g,
                                              const void* be, const void* al,
                                              float* zstats, unsigned int* out) {
  __shared__ alignas(16) short sW[16 * 128 * 8];  // 32 KB
  __shared__ float sSc[DD], sSh[DD], sAl;
  const int isbf = flags[1];
  const int tid = threadIdx.x;

  if (blockIdx.x < 64) zstats[blockIdx.x * 256 + tid] = 0.f;
  {
    const short8* src = (const short8*)wp;
    short8* dst = (short8*)sW;
#pragma unroll
    for (int i = 0; i < 8; i++) dst[tid + i * 256] = src[tid + i * 256];
  }
  if (XMODE == 2) {
    if (tid < DD) {
      float s = 0.f, q = 0.f;
#pragma unroll 8
      for (int k = 0; k < 64; k++) {
        s += statsp[k * 256 + tid];
        q += statsp[k * 256 + 128 + tid];
      }
      const float inv_n = 1.0f / NN;
      float mu = s * inv_n;
      float var = q * inv_n - mu * mu;
      float sc = rsqrtf(var + BN_EPS) * ldf(g, tid, isbf);
      sSc[tid] = sc;
      sSh[tid] = ldf(be, tid, isbf) - mu * sc;
    }
    if (tid == 0) sAl = ldf(al, 0, isbf);
  }
  __syncthreads();

  const int wave = tid >> 6;
  const int lane = tid & 63;
  const int quad = lane >> 4;
  const int m16 = lane & 15;
  const int r0 = blockIdx.x * 128 + wave * 32;

  f32x4 acc[2][8];
#pragma unroll
  for (int t = 0; t < 2; t++)
#pragma unroll
    for (int n = 0; n < 8; n++) acc[t][n] = (f32x4){0.f, 0.f, 0.f, 0.f};

#pragma unroll
  for (int q = 0; q < 4; q++) {
    const int kq = q * 32 + quad * 8;
    short8 af[2];
#pragma unroll
    for (int t = 0; t < 2; t++) {
      int row = r0 + t * 16 + m16;
      row = row < NN ? row : NN - 1;  // clamp; garbage rows never stored
      if (XMODE == 2) {
        short8 raw = *(const short8*)((const short*)in_ + (size_t)row * DD + kq);
        short8 f;
#pragma unroll
        for (int jj = 0; jj < 8; jj++) {
          float y = s2f(raw[jj]);
          y = y * sSc[kq + jj] + sSh[kq + jj];
          y = y > 0.f ? y : sAl * y;
          f[jj] = (short)f2bs(y);
        }
        af[t] = f;
      } else if (isbf) {
        af[t] = *(const short8*)((const short*)in_ + (size_t)row * DD + kq);
      } else {
        const float* ap = (const float*)in_ + (size_t)row * DD + kq;
        const float4 u0 = *(const float4*)ap;
        const float4 u1 = *(const float4*)(ap + 4);
        float v[8] = {u0.x, u0.y, u0.z, u0.w, u1.x, u1.y, u1.z, u1.w};
        short8 f;
#pragma unroll
        for (int jj = 0; jj < 8; jj++) f[jj] = (short)f2bs(v[jj]);
        af[t] = f;
      }
    }
    const int c = q * 4 + quad;
    const short* bp = sW + c * 1024 + m16 * 8;
#pragma unroll
    for (int n = 0; n < 8; n++) {
      const short8 bfrag = *(const short8*)(bp + n * 128);
      acc[0][n] = __builtin_amdgcn_mfma_f32_16x16x32_bf16(af[0], bfrag, acc[0][n], 0, 0, 0);
      acc[1][n] = __builtin_amdgcn_mfma_f32_16x16x32_bf16(af[1], bfrag, acc[1][n], 0, 0, 0);
    }
  }

#pragma unroll
  for (int t = 0; t < 2; t++)
#pragma unroll
    for (int r = 0; r < 4; r++) {
      int row = r0 + t * 16 + quad * 4 + r;
      if (row < NN) {
        float di = dinv[row];
        unsigned int* orow = out + (size_t)row * 64;
#pragma unroll
        for (int n = 0; n < 4; n++) {
          unsigned int p = (f2bs(di * acc[t][n + 4][r]) << 16) | f2bs(di * acc[t][n][r]);
          orow[n * 16 + m16] = p;
        }
      }
    }
}

// One wave per node (12500 blocks = 50000 waves exactly). Row range
// [rowptr[w], rowend[w]) in the gapped CSR. 8-deep gather unroll.
// Always accumulates per-block BN stats into statsp[blockIdx&63].
__global__ __launch_bounds__(256) void k_agg(const unsigned int* hs, const float* dinv,
                                             const int* rowptr, const int* rowend,
                                             const int* csr_src, const void* bias,
                                             const int* flags, unsigned short* out,
                                             float* statsp) {
  const int tid = threadIdx.x;
  int w = (blockIdx.x * 256 + tid) >> 6;   // never >= NN (12500*4 == NN)
  int lane = tid & 63;
  float dd_ = dinv[w];
  unsigned int hv = hs[(size_t)w * 64 + lane];
  float ax = bslo(hv), ay = bshi(hv);
  int e = rowptr[w], e1 = rowend[w];
  for (; e + 7 < e1; e += 8) {
    int s0 = csr_src[e], s1 = csr_src[e + 1], s2 = csr_src[e + 2], s3 = csr_src[e + 3];
    int s4 = csr_src[e + 4], s5 = csr_src[e + 5], s6 = csr_src[e + 6], s7 = csr_src[e + 7];
    unsigned int v0 = hs[(size_t)s0 * 64 + lane];
    unsigned int v1 = hs[(size_t)s1 * 64 + lane];
    unsigned int v2 = hs[(size_t)s2 * 64 + lane];
    unsigned int v3 = hs[(size_t)s3 * 64 + lane];
    unsigned int v4 = hs[(size_t)s4 * 64 + lane];
    unsigned int v5 = hs[(size_t)s5 * 64 + lane];
    unsigned int v6 = hs[(size_t)s6 * 64 + lane];
    unsigned int v7 = hs[(size_t)s7 * 64 + lane];
    ax += bslo(v0) + bslo(v1) + bslo(v2) + bslo(v3) + bslo(v4) + bslo(v5) + bslo(v6) + bslo(v7);
    ay += bshi(v0) + bshi(v1) + bshi(v2) + bshi(v3) + bshi(v4) + bshi(v5) + bshi(v6) + bshi(v7);
  }
  for (; e + 3 < e1; e += 4) {
    int s0 = csr_src[e], s1 = csr_src[e + 1], s2 = csr_src[e + 2], s3 = csr_src[e + 3];
    unsigned int v0 = hs[(size_t)s0 * 64 + lane];
    unsigned int v1 = hs[(size_t)s1 * 64 + lane];
    unsigned int v2 = hs[(size_t)s2 * 64 + lane];
    unsigned int v3 = hs[(size_t)s3 * 64 + lane];
    ax += bslo(v0) + bslo(v1) + bslo(v2) + bslo(v3);
    ay += bshi(v0) + bshi(v1) + bshi(v2) + bshi(v3);
  }
  for (; e < e1; e++) {
    unsigned int v0 = hs[(size_t)csr_src[e] * 64 + lane];
    ax += bslo(v0);
    ay += bshi(v0);
  }
  int isbf = flags[1];
  float o1 = dd_ * ax + ldf(bias, lane, isbf);
  float o2 = dd_ * ay + ldf(bias, lane + 64, isbf);
  unsigned short* orow = out + (size_t)w * DD;
  orow[lane] = (unsigned short)f2bs(o1);
  orow[lane + 64] = (unsigned short)f2bs(o2);

  __shared__ float rs1[256], rq1[256], rs2[256], rq2[256];
  rs1[tid] = o1; rq1[tid] = o1 * o1;
  rs2[tid] = o2; rq2[tid] = o2 * o2;
  __syncthreads();
  float* p = statsp + (blockIdx.x & 63) * 256;
  if (tid < 64) {  // col tid
    float s = rs1[tid] + rs1[tid + 64] + rs1[tid + 128] + rs1[tid + 192];
    float q = rq1[tid] + rq1[tid + 64] + rq1[tid + 128] + rq1[tid + 192];
    atomicAdd(&p[tid], s);
    atomicAdd(&p[128 + tid], q);
  } else if (tid < 128) {  // col tid (= 64 + lane)
    int l = tid - 64;
    float s = rs2[l] + rs2[l + 64] + rs2[l + 128] + rs2[l + 192];
    float q = rq2[l] + rq2[l + 64] + rq2[l + 128] + rq2[l + 192];
    atomicAdd(&p[tid], s);
    atomicAdd(&p[128 + tid], q);
  }
}

// Final BN+PReLU: 1024 grid-stride blocks. Prologue sums the 64 stat copies
// into LDS sc/sh (one rsqrt per column per block, not per element).
__global__ __launch_bounds__(256) void k_bn_apply(const unsigned int* x32, const float* statsp,
                                                  const void* g, const void* be, const void* al,
                                                  const int* flags, void* out) {
  __shared__ float sSc[DD], sSh[DD], sAl;
  const int tid = threadIdx.x;
  const int isbf = flags[1];
  if (tid < DD) {
    float s = 0.f, q = 0.f;
#pragma unroll 8
    for (int k = 0; k < 64; k++) {
      s += statsp[k * 256 + tid];
      q += statsp[k * 256 + 128 + tid];
    }
    const float inv_n = 1.0f / NN;
    float mu = s * inv_n;
    float var = q * inv_n - mu * mu;
    float sc = rsqrtf(var + BN_EPS) * ldf(g, tid, isbf);
    sSc[tid] = sc;
    sSh[tid] = ldf(be, tid, isbf) - mu * sc;
  }
  if (tid == 0) sAl = ldf(al, 0, isbf);
  __syncthreads();
  const float alpha = sAl;
  for (int i4 = blockIdx.x * 256 + tid; i4 < NN * 32; i4 += gridDim.x * 256) {
    int jq = (i4 & 31) * 4;
    const uint2 xv = ((const uint2*)x32)[i4];
    float xa[4] = {bslo(xv.x), bshi(xv.x), bslo(xv.y), bshi(xv.y)};
    float y[4];
#pragma unroll
    for (int u = 0; u < 4; u++) {
      int j = jq + u;
      float v = xa[u] * sSc[j] + sSh[j];
      y[u] = v > 0.f ? v : alpha * v;
    }
    if (isbf) {
      uint2 o;
      o.x = (f2bs(y[1]) << 16) | f2bs(y[0]);
      o.y = (f2bs(y[3]) << 16) | f2bs(y[2]);
      ((uint2*)out)[i4] = o;
    } else {
      float4 o = {y[0], y[1], y[2], y[3]};
      ((float4*)out)[i4] = o;
    }
  }
}

extern "C" void kernel_launch(void* const* d_in, const int* in_sizes, int n_in,
                              void* d_out, int out_size, void* d_ws, size_t ws_size,
                              hipStream_t stream) {
  const void* x = d_in[0];
  const int* ei = (const int*)d_in[1];
  const void* W1 = d_in[2];
  const void* b1 = d_in[3];
  const void* g1 = d_in[4];
  const void* be1 = d_in[5];
  const void* a1 = d_in[6];
  const void* W2 = d_in[7];
  const void* b2 = d_in[8];
  const void* g2 = d_in[9];
  const void* be2 = d_in[10];
  const void* a2 = d_in[11];

  char* w = (char*)d_ws;
  float* dinv = (float*)w;                              // 200000
  int* flags = (int*)(w + 200704);                      // 8
  int* rowptr = (int*)(w + 404800);                     // 200000
  int* rowend = (int*)(w + 604816);                     // 200000
  int* tailc = (int*)(w + 805632);                      // 256
  float* stats1p = (float*)(w + 806400);                // 65536
  float* stats2p = (float*)(w + 871936);                // 65536
  int* csr_src = (int*)(w + 1048576);                   // 3612672
  unsigned int* hbuf = (unsigned int*)(w + 4718592);    // 12800000
  unsigned short* wp1 = (unsigned short*)(w + 17518592);   // 32768
  unsigned short* wp2 = (unsigned short*)(w + 17551360);   // 32768
  unsigned short* aggbuf = (unsigned short*)(w + 30056448);  // 12800000
  unsigned int* binned = (unsigned int*)(w + 42856448);  // 3612672

  const int NB_G = (NN + 127) / 128;   // 391
  const int NB_W = NN * 64 / 256;      // 12500

  hipMemsetAsync(tailc, 0, 256, stream);
  k_bin<<<dim3(256), dim3(256), 0, stream>>>(ei, (const unsigned short*)x, W1, W2,
                                             wp1, wp2, flags, tailc, binned);
  k_degfill<<<dim3(NBKT), dim3(1024), 0, stream>>>(binned, tailc, dinv, rowptr, rowend,
                                                   csr_src);

  // ---- layer 1 ----
  k_gemm<0><<<dim3(NB_G), dim3(256), 0, stream>>>(x, wp1, flags, dinv,
                                                  nullptr, nullptr, nullptr, nullptr,
                                                  stats1p, hbuf);
  k_agg<<<dim3(NB_W), dim3(256), 0, stream>>>(hbuf, dinv, rowptr, rowend, csr_src,
                                              b1, flags, aggbuf, stats1p);

  // ---- layer 2 (BN1+PReLU fused into GEMM A-path via stats1p) ----
  k_gemm<2><<<dim3(NB_G), dim3(256), 0, stream>>>(aggbuf, wp2, flags, dinv,
                                                  stats1p, g1, be1, a1, stats2p, hbuf);
  k_agg<<<dim3(NB_W), dim3(256), 0, stream>>>(hbuf, dinv, rowptr, rowend, csr_src,
                                              b2, flags, aggbuf, stats2p);
  k_bn_apply<<<dim3(1024), dim3(256), 0, stream>>>((const unsigned int*)aggbuf, stats2p,
                                                   g2, be2, a2, flags, d_out);
}